// Round 9
// baseline (213.517 us; speedup 1.0000x reference)
//
#include <hip/hip_runtime.h>
#include <hip/hip_bf16.h>
#include <math.h>

#define N_NODES 156
#define NFEAT 256
#define NHID 128
#define BATCH 16384
#define TT 24
#define HLSTM 32
#define G4 128            // 4*HLSTM
#define ALPHA 0.2f
#define ROWS 8            // batch rows per block
#define XSTRIDE (TT*N_NODES)   // 3744 floats per batch row
#define XROWPAD 168       // bf16 cols per (t,row) in LDS (bank-spread, 156..159 zeroed)
#define XT (ROWS*XROWPAD) // 1344 ushorts per t-step

typedef __attribute__((ext_vector_type(8))) short bf16x8;
typedef __attribute__((ext_vector_type(4))) float f32x4;

static __device__ __forceinline__ unsigned short f2bf(float f) {
    unsigned u = __float_as_uint(f);
    u += 0x7fffu + ((u >> 16) & 1u);          // RNE
    return (unsigned short)(u >> 16);
}
static __device__ __forceinline__ bf16x8 cv8(float4 a, float4 b) {
    union { __hip_bfloat16 h[8]; bf16x8 v; } u;
    u.h[0] = __float2bfloat16(a.x); u.h[1] = __float2bfloat16(a.y);
    u.h[2] = __float2bfloat16(a.z); u.h[3] = __float2bfloat16(a.w);
    u.h[4] = __float2bfloat16(b.x); u.h[5] = __float2bfloat16(b.y);
    u.h[6] = __float2bfloat16(b.z); u.h[7] = __float2bfloat16(b.w);
    return u.v;
}
static __device__ __forceinline__ float sigm(float x) { return 1.f / (1.f + __expf(-x)); }
static __device__ __forceinline__ float tanh_(float x) { return 1.f - 2.f / (__expf(2.f * x) + 1.f); }

// ---------------- K1: GAT s1/s2 ----
__global__ void k_gat_s(const float* __restrict__ emb,
                        const float* __restrict__ Wr, const float* __restrict__ ar,
                        const float* __restrict__ Wp, const float* __restrict__ ap,
                        float* __restrict__ s_buf /* [2][2][156] */) {
    int i = blockIdx.x;
    int gat = blockIdx.y;
    const float* W = gat ? Wp : Wr;
    const float* a = gat ? ap : ar;
    int j = threadIdx.x; // 0..127
    __shared__ float erow[NFEAT];
    __shared__ float red[128];
    for (int k = j; k < NFEAT; k += 128) erow[k] = emb[i*NFEAT + k];
    __syncthreads();
    float h = 0.f;
    for (int k = 0; k < NFEAT; ++k) h = fmaf(erow[k], W[k*NHID + j], h);
    float v1 = h * a[j];
    float v2 = h * a[NHID + j];
    red[j] = v1; __syncthreads();
    for (int s = 64; s > 0; s >>= 1) { if (j < s) red[j] += red[j+s]; __syncthreads(); }
    if (j == 0) s_buf[(gat*2+0)*N_NODES + i] = red[0];
    __syncthreads();
    red[j] = v2; __syncthreads();
    for (int s = 64; s > 0; s >>= 1) { if (j < s) red[j] += red[j+s]; __syncthreads(); }
    if (j == 0) s_buf[(gat*2+1)*N_NODES + i] = red[0];
}

// ---------------- K2: masked leaky-relu softmax rows -> attn ----------------
__global__ void k_attn(const float* __restrict__ s_buf, const int* __restrict__ adj,
                       float* __restrict__ attn /* [2][156][156] */) {
    int i = blockIdx.x, gat = blockIdx.y;
    int j = threadIdx.x;
    __shared__ float red[256];
    float s1 = s_buf[(gat*2+0)*N_NODES + i];
    bool act = (j < N_NODES);
    float e = -INFINITY;
    if (act) {
        float s2 = s_buf[(gat*2+1)*N_NODES + j];
        float z = s1 + s2;
        z = (z > 0.f) ? z : ALPHA * z;
        if (adj[i*N_NODES + j] <= 0) z = -9e15f;
        e = z;
    }
    red[j] = e; __syncthreads();
    for (int s = 128; s > 0; s >>= 1) { if (j < s) red[j] = fmaxf(red[j], red[j+s]); __syncthreads(); }
    float m = red[0]; __syncthreads();
    float val = act ? __expf(e - m) : 0.f;
    red[j] = val; __syncthreads();
    for (int s = 128; s > 0; s >>= 1) { if (j < s) red[j] += red[j+s]; __syncthreads(); }
    float inv = 1.f / red[0];
    if (act) attn[(gat*N_NODES + i)*N_NODES + j] = val * inv;
}

// ---------------- K3: Mbf = bf16(Wih @ attn) zero-padded to K=160,
//                      Whhbf = bf16(Whh), bias = bih + bhh ------------------
__global__ void k_prep(const float* __restrict__ attn,
                       const float* __restrict__ Wih_r, const float* __restrict__ Wih_p,
                       const float* __restrict__ Whh_r, const float* __restrict__ Whh_p,
                       const float* __restrict__ bih_r, const float* __restrict__ bhh_r,
                       const float* __restrict__ bih_p, const float* __restrict__ bhh_p,
                       unsigned short* __restrict__ Mbf /* [2][128][160] */,
                       unsigned short* __restrict__ Whhbf /* [2][128][32] */,
                       float* __restrict__ bias2 /* [2][128] */) {
    int g = blockIdx.x, gat = blockIdx.y;
    const float* Wih = gat ? Wih_p : Wih_r;
    const float* A = attn + gat*N_NODES*N_NODES;
    int j = threadIdx.x;
    if (j < 160) {
        float acc = 0.f;
        if (j < N_NODES)
            for (int n = 0; n < N_NODES; ++n)
                acc = fmaf(Wih[g*N_NODES + n], A[n*N_NODES + j], acc);
        Mbf[(gat*G4 + g)*160 + j] = f2bf(acc);   // j>=156 -> 0
    }
    if (j < HLSTM)
        Whhbf[(gat*G4 + g)*HLSTM + j] = f2bf((gat ? Whh_p : Whh_r)[g*HLSTM + j]);
    if (g == 0 && j < G4)
        bias2[gat*G4 + j] = gat ? (bih_p[j] + bhh_p[j]) : (bih_r[j] + bhh_r[j]);
}

// ---------------- K4: LDS-resident fused kernel -----------------------------
// grid 2048, block 128 (2 waves, gate-split: w0 = i,g cols; w1 = f,o cols).
// Phase 1: stream this block's CONTIGUOUS 117 KB x-region (8 rows x 24 steps)
//          via coalesced float4 loads -> cvt -> bf16 LDS tile [24][8][168].
// Phase 2: all 24 LSTM steps purely from LDS (no HBM, no vmcnt). 2 barriers/step.
// MFMA uses 16-row tiles with rows 8-15 = duplicated row 7 (garbage): D row i
// depends only on A row i, and D rows 8-15 are discarded (lg<2 guards).
// LDS 65.6 KB -> 2 blocks/CU: one block streams while the other computes.
__global__ void __launch_bounds__(128, 1)
k_fused(const float* __restrict__ x,
        const unsigned short* __restrict__ Mbf,    // [2][128][160] bf16, k-padded 0
        const unsigned short* __restrict__ Whhbf,  // [2][128][32] bf16
        const float* __restrict__ bias2,           // [2][128]
        const float* __restrict__ fcW,             // [156][64] f32
        const float* __restrict__ fcb,             // [156]
        float* __restrict__ out) {                 // [16384][156] f32
    __shared__ __align__(16) unsigned short xl[TT*XT];    // 64512 B
    __shared__ __align__(16) unsigned short hfr[ROWS*40]; // 640 B  [8][40] bf16
    __shared__ __align__(16) float P_ls[8*64];            // 2048 B (hcat aliases)

    const int tid = threadIdx.x;
    const int w  = tid >> 6;          // wave: 0 = i,g  1 = f,o
    const int l  = tid & 63;
    const int lm = l & 15;            // MFMA A-row (batch row) / D-col
    const int lg = l >> 4;            // MFMA k-group / D-row-group
    const int rl = (lm < ROWS) ? lm : (ROWS - 1);   // clamped A-row
    const int b0 = blockIdx.x * ROWS;

    bf16x8 bfr[4][5];     // this wave's gates B: [nt][kf]
    bf16x8 wrec[4];
    float  bias_v[4];
    float  cst[8];
    unsigned short hrv[8], hpv[8];
    const int nbase = w ? 2 : 0;

#define LOAD_FRAGS(Mb, Wb, bs) do {                                          \
    _Pragma("unroll")                                                        \
    for (int nt = 0; nt < 4; ++nt) {                                         \
        int ntid = nbase + (nt & 1) + ((nt >> 1) << 2);                      \
        int n_ = ntid*16 + lm;                                               \
        _Pragma("unroll")                                                    \
        for (int kf = 0; kf < 5; ++kf)                                       \
            bfr[nt][kf] = *(const bf16x8*)((Mb) + n_*160 + kf*32 + lg*8);    \
        wrec[nt]   = *(const bf16x8*)((Wb) + n_*HLSTM + lg*8);               \
        bias_v[nt] = (bs)[n_];                                               \
    } } while (0)

#define LGKM0() asm volatile("s_waitcnt lgkmcnt(0)" ::: "memory")

    LOAD_FRAGS(Mbf, Whhbf, bias2);
    #pragma unroll
    for (int v = 0; v < 8; ++v) cst[v] = 0.f;

    // ---- Phase 1: contiguous stream -> bf16 LDS tile ----
    // Block's x region: 29952 floats = 7488 float4 (58 full sweeps + 64 tail).
    {
        const float4* gsrc = (const float4*)(x + (size_t)b0 * XSTRIDE);
#define STAGE1(FIDX) do {                                                     \
        int f_ = (FIDX);                                                      \
        float4 v_ = gsrc[f_];                                                 \
        int row_ = f_ / 936;                                                  \
        int rem_ = f_ - row_*936;                                             \
        int t_   = rem_ / 39;                                                 \
        int dq_  = rem_ - t_*39;                                              \
        union { __hip_bfloat16 h[4]; uint2 u; } cv_;                          \
        cv_.h[0] = __float2bfloat16(v_.x); cv_.h[1] = __float2bfloat16(v_.y); \
        cv_.h[2] = __float2bfloat16(v_.z); cv_.h[3] = __float2bfloat16(v_.w); \
        *(uint2*)(xl + t_*XT + row_*XROWPAD + dq_*4) = cv_.u;                 \
    } while (0)
        #pragma unroll 4
        for (int j = 0; j < 58; ++j) STAGE1(j*128 + tid);
        if (tid < 64) STAGE1(58*128 + tid);
#undef STAGE1
        // zero K-pad cols 156..159 for all 192 (t,row) pairs + hfr
        uint2 z = make_uint2(0u, 0u);
        if (tid < 192) { int t_ = tid >> 3, r_ = tid & 7;
                         *(uint2*)(xl + t_*XT + r_*XROWPAD + 156) = z; }
        { int i1 = tid + 128; if (i1 < 192) { int t_ = i1 >> 3, r_ = i1 & 7;
                         *(uint2*)(xl + t_*XT + r_*XROWPAD + 156) = z; } }
        if (tid < 80) *(uint2*)(hfr + tid*4) = z;
    }
    LGKM0();
    __builtin_amdgcn_s_barrier();      // x tile + zeroed h visible to both waves

    // ---- Phase 2: 24 steps from LDS ----
#define STEP(T_, STASH_, LAST_) do {                                          \
    bf16x8 af_[5];                                                            \
    { const unsigned short* xr_ = xl + (T_)*XT + rl*XROWPAD + lg*8;           \
      _Pragma("unroll")                                                       \
      for (int kf = 0; kf < 5; ++kf) af_[kf] = *(const bf16x8*)(xr_ + kf*32); } \
    LGKM0();                                                                  \
    __builtin_amdgcn_s_barrier();      /* h(T-1) from w1 visible */           \
    bf16x8 hf_ = *(const bf16x8*)(hfr + rl*40 + lg*8);                        \
    f32x4 acc[4];                                                             \
    _Pragma("unroll")                                                         \
    for (int nt = 0; nt < 4; ++nt)                                            \
        acc[nt] = (f32x4){bias_v[nt], bias_v[nt], bias_v[nt], bias_v[nt]};    \
    _Pragma("unroll")                                                         \
    for (int kf = 0; kf < 5; ++kf)                                            \
        _Pragma("unroll")                                                     \
        for (int nt = 0; nt < 4; ++nt)                                        \
            acc[nt] = __builtin_amdgcn_mfma_f32_16x16x32_bf16(af_[kf], bfr[nt][kf], acc[nt], 0, 0, 0); \
    _Pragma("unroll")                                                         \
    for (int nt = 0; nt < 4; ++nt)                                            \
        acc[nt] = __builtin_amdgcn_mfma_f32_16x16x32_bf16(hf_, wrec[nt], acc[nt], 0, 0, 0); \
    float sa_[8], sb_[8];                                                     \
    if (w == 0) {                                                             \
        _Pragma("unroll")                                                     \
        for (int ds = 0; ds < 2; ++ds)                                        \
            _Pragma("unroll")                                                 \
            for (int i = 0; i < 4; ++i)                                       \
                P_ls[(ds*4 + i)*64 + l] = sigm(acc[ds][i]) * tanh_(acc[2 + ds][i]); \
    } else {                                                                  \
        _Pragma("unroll")                                                     \
        for (int ds = 0; ds < 2; ++ds)                                        \
            _Pragma("unroll")                                                 \
            for (int i = 0; i < 4; ++i) {                                     \
                sa_[ds*4 + i] = sigm(acc[ds][i]);       /* sf */              \
                sb_[ds*4 + i] = sigm(acc[2 + ds][i]);   /* so */              \
            }                                                                 \
    }                                                                         \
    LGKM0();                                                                  \
    __builtin_amdgcn_s_barrier();      /* P visible */                        \
    if (w == 1 && lg < 2) {                                                   \
        _Pragma("unroll")                                                     \
        for (int ds = 0; ds < 2; ++ds)                                        \
            _Pragma("unroll")                                                 \
            for (int i = 0; i < 4; ++i) {                                     \
                int v = ds*4 + i;                                             \
                float c = sa_[v]*cst[v] + P_ls[v*64 + l];                     \
                float h = sb_[v]*tanh_(c);                                    \
                int r = lg*4 + i;                                             \
                int d = lm + 16*ds;                                           \
                if (STASH_) { hrv[v] = f2bf(h); hfr[r*40 + d] = 0; cst[v] = 0.f; } \
                else if (LAST_) { hpv[v] = f2bf(h); }                         \
                else { cst[v] = c; hfr[r*40 + d] = f2bf(h); }                 \
            }                                                                 \
    }                                                                         \
    } while (0)

    STEP(0, 0, 0);
    STEP(1, 0, 0);
    STEP(2, 0, 0);
    STEP(3, 1, 0);                      // stash h_r, reset state
    LOAD_FRAGS(Mbf + G4*160, Whhbf + G4*HLSTM, bias2 + G4);
    #pragma unroll 1
    for (int t = 4; t < TT-1; ++t) STEP(t, 0, 0);
    STEP(TT-1, 0, 1);                   // keep h_p in regs

    // ---- fc epilogue: out = [hr|hp] @ fcW^T + fcb (MFMA, K=64) ----
    unsigned short* hcat = (unsigned short*)P_ls;   // [8][72] bf16 (aliases P_ls)
    if (w == 1 && lg < 2) {
        #pragma unroll
        for (int ds = 0; ds < 2; ++ds)
            #pragma unroll
            for (int i = 0; i < 4; ++i) {
                int r = lg*4 + i, d = lm + 16*ds, v = ds*4 + i;
                hcat[r*72 + d]      = hrv[v];
                hcat[r*72 + 32 + d] = hpv[v];
            }
    }
    LGKM0();
    __builtin_amdgcn_s_barrier();
    {
        bf16x8 ha0 = *(const bf16x8*)(hcat + rl*72 + lg*8);
        bf16x8 ha1 = *(const bf16x8*)(hcat + rl*72 + 32 + lg*8);
        #pragma unroll
        for (int nt5 = 0; nt5 < 5; ++nt5) {
            int nt = w*5 + nt5;
            int n  = nt*16 + lm;
            int nc = n < 155 ? n : 155;
            const float* wp0 = fcW + nc*64 + lg*8;
            const float* wp1 = fcW + nc*64 + 32 + lg*8;
            bf16x8 wf0 = cv8(*(const float4*)wp0, *(const float4*)(wp0 + 4));
            bf16x8 wf1 = cv8(*(const float4*)wp1, *(const float4*)(wp1 + 4));
            f32x4 fa = (f32x4){0.f, 0.f, 0.f, 0.f};
            fa = __builtin_amdgcn_mfma_f32_16x16x32_bf16(ha0, wf0, fa, 0, 0, 0);
            fa = __builtin_amdgcn_mfma_f32_16x16x32_bf16(ha1, wf1, fa, 0, 0, 0);
            if (n < N_NODES && lg < 2) {
                float bn = fcb[n];
                #pragma unroll
                for (int i = 0; i < 4; ++i)
                    out[(size_t)(b0 + lg*4 + i)*N_NODES + n] = fa[i] + bn;
            }
        }
    }
#undef STEP
#undef LGKM0
#undef LOAD_FRAGS
}

extern "C" void kernel_launch(void* const* d_in, const int* in_sizes, int n_in,
                              void* d_out, int out_size, void* d_ws, size_t ws_size,
                              hipStream_t stream) {
    (void)in_sizes; (void)n_in; (void)out_size; (void)ws_size;
    const float* emb   = (const float*)d_in[0];
    const float* x     = (const float*)d_in[1];
    const int*   adj   = (const int*)d_in[2];
    const float* Wr    = (const float*)d_in[3];
    const float* ar    = (const float*)d_in[4];
    const float* Wp    = (const float*)d_in[5];
    const float* ap    = (const float*)d_in[6];
    const float* Wih_r = (const float*)d_in[7];
    const float* Whh_r = (const float*)d_in[8];
    const float* bih_r = (const float*)d_in[9];
    const float* bhh_r = (const float*)d_in[10];
    const float* Wih_p = (const float*)d_in[11];
    const float* Whh_p = (const float*)d_in[12];
    const float* bih_p = (const float*)d_in[13];
    const float* bhh_p = (const float*)d_in[14];
    const float* fcW   = (const float*)d_in[15];
    const float* fcb   = (const float*)d_in[16];
    float* out = (float*)d_out;

    char* ws = (char*)d_ws;
    size_t off = 0;
    auto alloc = [&](size_t bytes) {
        char* p = ws + off;
        off += (bytes + 255) & ~(size_t)255;
        return p;
    };
    float*          attn  = (float*)alloc(2*156*156*sizeof(float));
    float*          sbuf  = (float*)alloc(4*156*sizeof(float));
    unsigned short* Mbf   = (unsigned short*)alloc(2*G4*160*sizeof(unsigned short));
    unsigned short* Whhbf = (unsigned short*)alloc(2*G4*HLSTM*sizeof(unsigned short));
    float*          bias2 = (float*)alloc(2*G4*sizeof(float));

    k_gat_s<<<dim3(156, 2), 128, 0, stream>>>(emb, Wr, ar, Wp, ap, sbuf);
    k_attn<<<dim3(156, 2), 256, 0, stream>>>(sbuf, adj, attn);
    k_prep<<<dim3(128, 2), 192, 0, stream>>>(attn, Wih_r, Wih_p, Whh_r, Whh_p,
                                             bih_r, bhh_r, bih_p, bhh_p,
                                             Mbf, Whhbf, bias2);
    k_fused<<<dim3(BATCH/ROWS), 128, 0, stream>>>(x, Mbf, Whhbf, bias2, fcW, fcb, out);
}

// Round 11
// 155.044 us; speedup vs baseline: 1.3771x; 1.3771x over previous
//
#include <hip/hip_runtime.h>
#include <hip/hip_bf16.h>
#include <math.h>

#define N_NODES 156
#define NFEAT 256
#define NHID 128
#define BATCH 16384
#define TT 24
#define HLSTM 32
#define G4 128            // 4*HLSTM
#define ALPHA 0.2f
#define XSTRIDE (TT*N_NODES)   // 3744 floats per batch row
#define XROWPAD 168       // bf16 cols per (t,row) image row
#define XT (16*XROWPAD)   // 2688 ushorts per t-step image

typedef __attribute__((ext_vector_type(8))) short bf16x8;
typedef __attribute__((ext_vector_type(4))) float f32x4;

static __device__ __forceinline__ unsigned short f2bf(float f) {
    unsigned u = __float_as_uint(f);
    u += 0x7fffu + ((u >> 16) & 1u);          // RNE
    return (unsigned short)(u >> 16);
}
static __device__ __forceinline__ bf16x8 cv8(float4 a, float4 b) {
    union { __hip_bfloat16 h[8]; bf16x8 v; } u;
    u.h[0] = __float2bfloat16(a.x); u.h[1] = __float2bfloat16(a.y);
    u.h[2] = __float2bfloat16(a.z); u.h[3] = __float2bfloat16(a.w);
    u.h[4] = __float2bfloat16(b.x); u.h[5] = __float2bfloat16(b.y);
    u.h[6] = __float2bfloat16(b.z); u.h[7] = __float2bfloat16(b.w);
    return u.v;
}
static __device__ __forceinline__ float sigm(float x) { return 1.f / (1.f + __expf(-x)); }
static __device__ __forceinline__ float tanh_(float x) { return 1.f - 2.f / (__expf(2.f * x) + 1.f); }

// ---------------- K1: GAT s1/s2 ----
__global__ void k_gat_s(const float* __restrict__ emb,
                        const float* __restrict__ Wr, const float* __restrict__ ar,
                        const float* __restrict__ Wp, const float* __restrict__ ap,
                        float* __restrict__ s_buf /* [2][2][156] */) {
    int i = blockIdx.x;
    int gat = blockIdx.y;
    const float* W = gat ? Wp : Wr;
    const float* a = gat ? ap : ar;
    int j = threadIdx.x; // 0..127
    __shared__ float erow[NFEAT];
    __shared__ float red[128];
    for (int k = j; k < NFEAT; k += 128) erow[k] = emb[i*NFEAT + k];
    __syncthreads();
    float h = 0.f;
    for (int k = 0; k < NFEAT; ++k) h = fmaf(erow[k], W[k*NHID + j], h);
    float v1 = h * a[j];
    float v2 = h * a[NHID + j];
    red[j] = v1; __syncthreads();
    for (int s = 64; s > 0; s >>= 1) { if (j < s) red[j] += red[j+s]; __syncthreads(); }
    if (j == 0) s_buf[(gat*2+0)*N_NODES + i] = red[0];
    __syncthreads();
    red[j] = v2; __syncthreads();
    for (int s = 64; s > 0; s >>= 1) { if (j < s) red[j] += red[j+s]; __syncthreads(); }
    if (j == 0) s_buf[(gat*2+1)*N_NODES + i] = red[0];
}

// ---------------- K2: masked leaky-relu softmax rows -> attn ----------------
__global__ void k_attn(const float* __restrict__ s_buf, const int* __restrict__ adj,
                       float* __restrict__ attn /* [2][156][156] */) {
    int i = blockIdx.x, gat = blockIdx.y;
    int j = threadIdx.x;
    __shared__ float red[256];
    float s1 = s_buf[(gat*2+0)*N_NODES + i];
    bool act = (j < N_NODES);
    float e = -INFINITY;
    if (act) {
        float s2 = s_buf[(gat*2+1)*N_NODES + j];
        float z = s1 + s2;
        z = (z > 0.f) ? z : ALPHA * z;
        if (adj[i*N_NODES + j] <= 0) z = -9e15f;
        e = z;
    }
    red[j] = e; __syncthreads();
    for (int s = 128; s > 0; s >>= 1) { if (j < s) red[j] = fmaxf(red[j], red[j+s]); __syncthreads(); }
    float m = red[0]; __syncthreads();
    float val = act ? __expf(e - m) : 0.f;
    red[j] = val; __syncthreads();
    for (int s = 128; s > 0; s >>= 1) { if (j < s) red[j] += red[j+s]; __syncthreads(); }
    float inv = 1.f / red[0];
    if (act) attn[(gat*N_NODES + i)*N_NODES + j] = val * inv;
}

// ---------------- K3: Mbf = bf16(Wih @ attn) zero-padded to K=160,
//                      Whhbf = bf16(Whh), bias = bih + bhh ------------------
__global__ void k_prep(const float* __restrict__ attn,
                       const float* __restrict__ Wih_r, const float* __restrict__ Wih_p,
                       const float* __restrict__ Whh_r, const float* __restrict__ Whh_p,
                       const float* __restrict__ bih_r, const float* __restrict__ bhh_r,
                       const float* __restrict__ bih_p, const float* __restrict__ bhh_p,
                       unsigned short* __restrict__ Mbf /* [2][128][160] */,
                       unsigned short* __restrict__ Whhbf /* [2][128][32] */,
                       float* __restrict__ bias2 /* [2][128] */) {
    int g = blockIdx.x, gat = blockIdx.y;
    const float* Wih = gat ? Wih_p : Wih_r;
    const float* A = attn + gat*N_NODES*N_NODES;
    int j = threadIdx.x;
    if (j < 160) {
        float acc = 0.f;
        if (j < N_NODES)
            for (int n = 0; n < N_NODES; ++n)
                acc = fmaf(Wih[g*N_NODES + n], A[n*N_NODES + j], acc);
        Mbf[(gat*G4 + g)*160 + j] = f2bf(acc);   // j>=156 -> 0
    }
    if (j < HLSTM)
        Whhbf[(gat*G4 + g)*HLSTM + j] = f2bf((gat ? Whh_p : Whh_r)[g*HLSTM + j]);
    if (g == 0 && j < G4)
        bias2[gat*G4 + j] = gat ? (bih_p[j] + bhh_p[j]) : (bih_r[j] + bhh_r[j]);
}

// ---------------- K4: fused gates-MFMA + LSTM + fc --------------------------
// grid 1024, block 128 (2 waves, gate-split: w0 = i,g cols; w1 = f,o cols).
// x staged in GROUPS of 4 steps via register loads: thread (row=tid>>3,
// seg=tid&7) reads its row's CONTIGUOUS 2496B run as 19.5 float4 (full 128B
// transactions, deep ILP, issued ~2 steps early), cvt -> bf16 ring-2 LDS
// image [2][4][16][168]. No vmcnt asm; lgkm+barrier per group only.
// NaN FIX vs R10: K-pad cols 156..159 of every image row zeroed at init
// (SWRITE only fills 0..155; STEP reads 0..159).
__global__ void __launch_bounds__(128, 2)
k_fused(const float* __restrict__ x,
        const unsigned short* __restrict__ Mbf,    // [2][128][160] bf16, k-padded 0
        const unsigned short* __restrict__ Whhbf,  // [2][128][32] bf16
        const float* __restrict__ bias2,           // [2][128]
        const float* __restrict__ fcW,             // [156][64] f32
        const float* __restrict__ fcb,             // [156]
        float* __restrict__ out) {                 // [16384][156] f32
    __shared__ __align__(16) unsigned short xb[2*4*XT];      // 43008 B ring-2 x-image
    __shared__ __align__(16) unsigned short hfr[512];        // 1 KB frag-linear h
    __shared__ __align__(16) float P_ls[512];                // 2 KB [8][64]
    __shared__ __align__(16) unsigned short hcat[16*72];     // 2.25 KB

    const int tid = threadIdx.x;
    const int w  = tid >> 6;          // wave: 0 = i,g  1 = f,o
    const int l  = tid & 63;
    const int lm = l & 15;
    const int lg = l >> 4;
    const int b0 = blockIdx.x * 16;
    const int srow = tid >> 3;        // staging row 0..15
    const int sseg = tid & 7;         // staging segment within row
    const float* xrow = x + (size_t)(b0 + srow) * XSTRIDE;

    bf16x8 bfr[4][5];     // this wave's gates B: [nt][kf]
    bf16x8 wrec[4];
    float  bias_v[4];
    float  cst[8];
    unsigned short hrv[8], hpv[8];
    const int nbase = w ? 2 : 0;

#define LOAD_FRAGS(Mb, Wb, bs) do {                                          \
    _Pragma("unroll")                                                        \
    for (int nt = 0; nt < 4; ++nt) {                                         \
        int ntid = nbase + (nt & 1) + ((nt >> 1) << 2);                      \
        int n_ = ntid*16 + lm;                                               \
        _Pragma("unroll")                                                    \
        for (int kf = 0; kf < 5; ++kf)                                       \
            bfr[nt][kf] = *(const bf16x8*)((Mb) + n_*160 + kf*32 + lg*8);    \
        wrec[nt]   = *(const bf16x8*)((Wb) + n_*HLSTM + lg*8);               \
        bias_v[nt] = (bs)[n_];                                               \
    } } while (0)

#define LGKM0() asm volatile("s_waitcnt lgkmcnt(0)" ::: "memory")

    // ---- staging: group G (steps 4G..4G+3), 2496B contiguous run per row ----
    // half H: k = H*10 .. H*10+9 (k==19 tail only sseg<4)
#define SLOAD(V_, G_, H_) do {                                                \
    const float* rp_ = xrow + (size_t)(G_)*624;                               \
    _Pragma("unroll")                                                         \
    for (int k_ = 0; k_ < 10; ++k_) {                                         \
        int kk_ = (H_)*10 + k_;                                               \
        if (kk_ < 19)      V_[k_] = *(const float4*)(rp_ + (sseg + 8*kk_)*4); \
        else if (sseg < 4) V_[k_] = *(const float4*)(rp_ + (sseg + 152)*4);   \
    } } while (0)

#define SWRITE(V_, BUF_, H_) do {                                             \
    _Pragma("unroll")                                                         \
    for (int k_ = 0; k_ < 10; ++k_) {                                         \
        int kk_ = (H_)*10 + k_;                                               \
        if (kk_ < 19 || sseg < 4) {                                           \
            int f4_ = (kk_ < 19) ? (sseg + 8*kk_) : (sseg + 152);             \
            int col_ = 4*f4_;                                                 \
            int ts_ = (col_ >= 468) ? 3 : (col_ >= 312) ? 2 :                 \
                      (col_ >= 156) ? 1 : 0;                                  \
            int dc_ = col_ - ts_*156;                                         \
            union { __hip_bfloat16 h[4]; uint2 u; } cv_;                      \
            cv_.h[0] = __float2bfloat16(V_[k_].x);                            \
            cv_.h[1] = __float2bfloat16(V_[k_].y);                            \
            cv_.h[2] = __float2bfloat16(V_[k_].z);                            \
            cv_.h[3] = __float2bfloat16(V_[k_].w);                            \
            *(uint2*)(xb + ((BUF_)*4 + ts_)*XT + srow*XROWPAD + dc_) = cv_.u; \
        }                                                                     \
    } } while (0)

#define STEP(TS_, CUR_, STASH_, LAST_) do {                                   \
    LGKM0();                                                                  \
    __builtin_amdgcn_s_barrier();   /* x image + h(T-1) visible */            \
    const unsigned short* xr_ = xb + ((CUR_)*4 + (TS_))*XT + lm*XROWPAD + lg*8; \
    bf16x8 af_[5];                                                            \
    _Pragma("unroll")                                                         \
    for (int kf = 0; kf < 5; ++kf) af_[kf] = *(const bf16x8*)(xr_ + kf*32);   \
    bf16x8 hf_ = *(const bf16x8*)(hfr + l*8);                                 \
    f32x4 acc[4];                                                             \
    _Pragma("unroll")                                                         \
    for (int nt = 0; nt < 4; ++nt)                                            \
        acc[nt] = (f32x4){bias_v[nt], bias_v[nt], bias_v[nt], bias_v[nt]};    \
    _Pragma("unroll")                                                         \
    for (int kf = 0; kf < 5; ++kf)                                            \
        _Pragma("unroll")                                                     \
        for (int nt = 0; nt < 4; ++nt)                                        \
            acc[nt] = __builtin_amdgcn_mfma_f32_16x16x32_bf16(af_[kf], bfr[nt][kf], acc[nt], 0, 0, 0); \
    _Pragma("unroll")                                                         \
    for (int nt = 0; nt < 4; ++nt)                                            \
        acc[nt] = __builtin_amdgcn_mfma_f32_16x16x32_bf16(hf_, wrec[nt], acc[nt], 0, 0, 0); \
    float sa_[8], sb_[8];                                                     \
    if (w == 0) {                                                             \
        _Pragma("unroll")                                                     \
        for (int ds = 0; ds < 2; ++ds)                                        \
            _Pragma("unroll")                                                 \
            for (int i = 0; i < 4; ++i)                                       \
                P_ls[(ds*4 + i)*64 + l] = sigm(acc[ds][i]) * tanh_(acc[2 + ds][i]); \
    } else {                                                                  \
        _Pragma("unroll")                                                     \
        for (int ds = 0; ds < 2; ++ds)                                        \
            _Pragma("unroll")                                                 \
            for (int i = 0; i < 4; ++i) {                                     \
                sa_[ds*4 + i] = sigm(acc[ds][i]);       /* sf */              \
                sb_[ds*4 + i] = sigm(acc[2 + ds][i]);   /* so */              \
            }                                                                 \
    }                                                                         \
    LGKM0();                                                                  \
    __builtin_amdgcn_s_barrier();   /* P published, all slot reads done */    \
    if (w == 1) {                                                             \
        _Pragma("unroll")                                                     \
        for (int ds = 0; ds < 2; ++ds)                                        \
            _Pragma("unroll")                                                 \
            for (int i = 0; i < 4; ++i) {                                     \
                int v = ds*4 + i;                                             \
                float c = sa_[v]*cst[v] + P_ls[v*64 + l];                     \
                float h = sb_[v]*tanh_(c);                                    \
                int cidx = ((lm>>3) + 2*ds)*128 + (lg*4 + i)*8 + (lm&7);      \
                if (STASH_)      { hrv[v] = f2bf(h); hfr[cidx] = 0; cst[v] = 0.f; } \
                else if (LAST_)  { hpv[v] = f2bf(h); }                        \
                else             { cst[v] = c; hfr[cidx] = f2bf(h); }         \
            }                                                                 \
    }                                                                         \
    } while (0)

    LOAD_FRAGS(Mbf, Whhbf, bias2);
    #pragma unroll
    for (int v = 0; v < 8; ++v) cst[v] = 0.f;
    if (w == 1) {                     // zero h-state (w1's 512 cells cover all)
        #pragma unroll
        for (int ds = 0; ds < 2; ++ds)
            #pragma unroll
            for (int i = 0; i < 4; ++i)
                hfr[((lm>>3) + 2*ds)*128 + (lg*4 + i)*8 + (lm&7)] = 0;
    }
    // NaN FIX: zero K-pad cols 156..159 of all 128 (buf,ts,row) image rows.
    // 128 threads x 1 row each; visible to readers via STEP's first barrier.
    *(uint2*)(xb + tid*XROWPAD + 156) = make_uint2(0u, 0u);

    float4 va[10], vb[10];
    // prologue: stage group 0 -> buf 0
    SLOAD(va, 0, 0); SWRITE(va, 0, 0);
    SLOAD(vb, 0, 1); SWRITE(vb, 0, 1);

    // ---- group 0 (buf0): steps 0..3; stash h_r at t=3; stage g1 -> buf1 ----
    SLOAD(va, 1, 0);
    STEP(0, 0, 0, 0);
    STEP(1, 0, 0, 0);
    SWRITE(va, 1, 0); SLOAD(vb, 1, 1);
    STEP(2, 0, 0, 0);
    STEP(3, 0, 1, 0);
    LOAD_FRAGS(Mbf + G4*160, Whhbf + G4*HLSTM, bias2 + G4);
    SWRITE(vb, 1, 1);

    // ---- groups 1..4 ----
    for (int g = 1; g <= 4; ++g) {
        int cur = g & 1, nxt = cur ^ 1;
        SLOAD(va, g + 1, 0);
        STEP(0, cur, 0, 0);
        STEP(1, cur, 0, 0);
        SWRITE(va, nxt, 0); SLOAD(vb, g + 1, 1);
        STEP(2, cur, 0, 0);
        STEP(3, cur, 0, 0);
        SWRITE(vb, nxt, 1);
    }

    // ---- group 5 (buf1): steps 20..23; keep h_p at t=23 ----
    STEP(0, 1, 0, 0);
    STEP(1, 1, 0, 0);
    STEP(2, 1, 0, 0);
    STEP(3, 1, 0, 1);

    // ---- fc epilogue: out = [hr|hp] @ fcW^T + fcb (MFMA, K=64) ----
    if (w == 1) {
        #pragma unroll
        for (int ds = 0; ds < 2; ++ds)
            #pragma unroll
            for (int i = 0; i < 4; ++i) {
                int r = lg*4 + i, d = lm + 16*ds, v = ds*4 + i;
                hcat[r*72 + d]      = hrv[v];
                hcat[r*72 + 32 + d] = hpv[v];
            }
    }
    LGKM0();
    __builtin_amdgcn_s_barrier();
    {
        bf16x8 ha0 = *(const bf16x8*)(hcat + lm*72 + lg*8);
        bf16x8 ha1 = *(const bf16x8*)(hcat + lm*72 + 32 + lg*8);
        #pragma unroll
        for (int nt5 = 0; nt5 < 5; ++nt5) {
            int nt = w*5 + nt5;
            int n  = nt*16 + lm;
            int nc = n < 155 ? n : 155;
            const float* wp0 = fcW + nc*64 + lg*8;
            const float* wp1 = fcW + nc*64 + 32 + lg*8;
            bf16x8 wf0 = cv8(*(const float4*)wp0, *(const float4*)(wp0 + 4));
            bf16x8 wf1 = cv8(*(const float4*)wp1, *(const float4*)(wp1 + 4));
            f32x4 fa = (f32x4){0.f, 0.f, 0.f, 0.f};
            fa = __builtin_amdgcn_mfma_f32_16x16x32_bf16(ha0, wf0, fa, 0, 0, 0);
            fa = __builtin_amdgcn_mfma_f32_16x16x32_bf16(ha1, wf1, fa, 0, 0, 0);
            if (n < N_NODES) {
                float bn = fcb[n];
                #pragma unroll
                for (int i = 0; i < 4; ++i)
                    out[(size_t)(b0 + lg*4 + i)*N_NODES + n] = fa[i] + bn;
            }
        }
    }
#undef STEP
#undef SWRITE
#undef SLOAD
#undef LGKM0
#undef LOAD_FRAGS
}

extern "C" void kernel_launch(void* const* d_in, const int* in_sizes, int n_in,
                              void* d_out, int out_size, void* d_ws, size_t ws_size,
                              hipStream_t stream) {
    (void)in_sizes; (void)n_in; (void)out_size; (void)ws_size;
    const float* emb   = (const float*)d_in[0];
    const float* x     = (const float*)d_in[1];
    const int*   adj   = (const int*)d_in[2];
    const float* Wr    = (const float*)d_in[3];
    const float* ar    = (const float*)d_in[4];
    const float* Wp    = (const float*)d_in[5];
    const float* ap    = (const float*)d_in[6];
    const float* Wih_r = (const float*)d_in[7];
    const float* Whh_r = (const float*)d_in[8];
    const float* bih_r = (const float*)d_in[9];
    const float* bhh_r = (const float*)d_in[10];
    const float* Wih_p = (const float*)d_in[11];
    const float* Whh_p = (const float*)d_in[12];
    const float* bih_p = (const float*)d_in[13];
    const float* bhh_p = (const float*)d_in[14];
    const float* fcW   = (const float*)d_in[15];
    const float* fcb   = (const float*)d_in[16];
    float* out = (float*)d_out;

    char* ws = (char*)d_ws;
    size_t off = 0;
    auto alloc = [&](size_t bytes) {
        char* p = ws + off;
        off += (bytes + 255) & ~(size_t)255;
        return p;
    };
    float*          attn  = (float*)alloc(2*156*156*sizeof(float));
    float*          sbuf  = (float*)alloc(4*156*sizeof(float));
    unsigned short* Mbf   = (unsigned short*)alloc(2*G4*160*sizeof(unsigned short));
    unsigned short* Whhbf = (unsigned short*)alloc(2*G4*HLSTM*sizeof(unsigned short));
    float*          bias2 = (float*)alloc(2*G4*sizeof(float));

    k_gat_s<<<dim3(156, 2), 128, 0, stream>>>(emb, Wr, ar, Wp, ap, sbuf);
    k_attn<<<dim3(156, 2), 256, 0, stream>>>(sbuf, adj, attn);
    k_prep<<<dim3(128, 2), 192, 0, stream>>>(attn, Wih_r, Wih_p, Whh_r, Whh_p,
                                             bih_r, bhh_r, bih_p, bhh_p,
                                             Mbf, Whhbf, bias2);
    k_fused<<<dim3(BATCH/16), 128, 0, stream>>>(x, Mbf, Whhbf, bias2, fcW, fcb, out);
}